// Round 5
// baseline (161.145 us; speedup 1.0000x reference)
//
#include <hip/hip_runtime.h>
#include <hip/hip_bf16.h>

#define EPS 1e-3f
#define QKSCALE 0.17677669529663689f

typedef __attribute__((ext_vector_type(8))) short bf16x8;
typedef __attribute__((ext_vector_type(4))) float f32x4;
typedef __attribute__((ext_vector_type(4))) unsigned short u16x4;
typedef __attribute__((ext_vector_type(8))) unsigned short u16x8;
typedef __attribute__((ext_vector_type(2))) unsigned int u32x2;

__device__ __forceinline__ unsigned short f2bf(float f) {
    union { float f; unsigned u; } v; v.f = f;
    unsigned r = v.u + 0x7FFFu + ((v.u >> 16) & 1u);
    return (unsigned short)(r >> 16);
}
__device__ __forceinline__ float bf2f(unsigned short h) {
    union { unsigned u; float f; } v; v.u = ((unsigned)h) << 16;
    return v.f;
}
__device__ __forceinline__ unsigned pkbf(float lo, float hi) {
    float2 t; t.x = lo; t.y = hi;
    __hip_bfloat162 h = __float22bfloat162_rn(t);
    union { __hip_bfloat162 h; unsigned u; } c; c.h = h;
    return c.u;
}

// ---------- convert both weight matrices to bf16 ----------
__global__ __launch_bounds__(256) void convw_kernel(
    const float* __restrict__ wq, const float* __restrict__ wc,
    unsigned short* __restrict__ wqb, unsigned short* __restrict__ wcb)
{
    int i = (blockIdx.x * 256 + threadIdx.x) * 4;
    const float* src; unsigned short* dst; int off;
    if (i < 131072) { src = wq; dst = wqb; off = i; }
    else            { src = wc; dst = wcb; off = i - 131072; }
    f32x4 v = *(const f32x4*)(src + off);
    u16x4 o;
    #pragma unroll
    for (int j = 0; j < 4; ++j) o[j] = f2bf(v[j]);
    *(u16x4*)(dst + off) = o;
}

// ---------- x [b][c][l] f32 -> xt [b][l][c] bf16 (LDS tile transpose) ----------
__global__ __launch_bounds__(256) void convx_kernel(
    const float* __restrict__ x, unsigned short* __restrict__ xt)
{
    __shared__ float t[64][65];
    int l0 = blockIdx.x * 64, c0 = blockIdx.y * 64, b = blockIdx.z;
    const float* xb = x + ((size_t)b * 256 + c0) * 1600 + l0;
    int tid = threadIdx.x;
    #pragma unroll
    for (int p = 0; p < 4; ++p) {
        int row = p * 16 + (tid >> 4);
        int col = (tid & 15) * 4;
        f32x4 v = *(const f32x4*)(xb + (size_t)row * 1600 + col);
        #pragma unroll
        for (int j = 0; j < 4; ++j) t[row][col + j] = v[j];
    }
    __syncthreads();
    int l = tid >> 2, cs = tid & 3;
    u16x8 o0, o1;
    #pragma unroll
    for (int i = 0; i < 8; ++i) o0[i] = f2bf(t[cs * 16 + i][l]);
    #pragma unroll
    for (int i = 0; i < 8; ++i) o1[i] = f2bf(t[cs * 16 + 8 + i][l]);
    unsigned short* dst = xt + ((size_t)b * 1600 + l0 + l) * 256 + c0 + cs * 16;
    *(u16x8*)dst = o0;
    *(u16x8*)(dst + 8) = o1;
}

// ---------- qkv = BN(qkv_w @ x) via MFMA; writes qk [b][n][l][64], vt [b][n][d][l] ----------
__global__ __launch_bounds__(256) void qkv_gemm_kernel(
    const unsigned short* __restrict__ wqb, const unsigned short* __restrict__ xt,
    const float* __restrict__ gg, const float* __restrict__ bet,
    const float* __restrict__ mm, const float* __restrict__ vv,
    unsigned short* __restrict__ qk, unsigned short* __restrict__ vt)
{
    const int tid = threadIdx.x, wid = tid >> 6, lane = tid & 63;
    const int g = lane >> 4, cc = lane & 15;
    const int l0 = blockIdx.x * 64;
    const int by = blockIdx.y;
    const int b  = blockIdx.z;
    const int o_base = by * 64 + wid * 16;

    const unsigned short* wb = wqb + (size_t)(o_base + cc) * 256;
    const unsigned short* xb = xt + ((size_t)b * 1600 + l0 + cc) * 256;

    const f32x4 fzero = {0.f, 0.f, 0.f, 0.f};
    f32x4 acc[4] = {fzero, fzero, fzero, fzero};
    #pragma unroll 4
    for (int kk = 0; kk < 256; kk += 32) {
        bf16x8 af = *(const bf16x8*)(wb + kk + 8 * g);
        #pragma unroll
        for (int f = 0; f < 4; ++f) {
            bf16x8 bfr = *(const bf16x8*)(xb + (size_t)f * 16 * 256 + kk + 8 * g);
            acc[f] = __builtin_amdgcn_mfma_f32_16x16x32_bf16(af, bfr, acc[f], 0, 0, 0);
        }
    }

    const int head = by >> 1;
    float inv[4], bias[4];
    #pragma unroll
    for (int r = 0; r < 4; ++r) {
        int oc = o_base + 4 * g + r;
        float iv = gg[oc] * rsqrtf(vv[oc] + EPS);
        float bs = bet[oc] - mm[oc] * iv;
        if ((oc & 127) < 32) { iv *= QKSCALE; bs *= QKSCALE; }
        inv[r] = iv; bias[r] = bs;
    }

    if (!(by & 1)) {
        unsigned short* dst = qk + ((size_t)(b * 4 + head) * 1600) * 64;
        #pragma unroll
        for (int f = 0; f < 4; ++f) {
            int l = l0 + 16 * f + cc;
            u16x4 pk;
            #pragma unroll
            for (int r = 0; r < 4; ++r) pk[r] = f2bf(acc[f][r] * inv[r] + bias[r]);
            *(u16x4*)(dst + (size_t)l * 64 + wid * 16 + 4 * g) = pk;
        }
    } else {
        unsigned short* dst = vt + ((size_t)(b * 4 + head) * 64) * 1600;
        #pragma unroll
        for (int f = 0; f < 4; ++f) {
            int l = l0 + 16 * f + cc;
            #pragma unroll
            for (int r = 0; r < 4; ++r) {
                int d = wid * 16 + 4 * g + r;
                dst[(size_t)d * 1600 + l] = f2bf(acc[f][r] * inv[r] + bias[r]);
            }
        }
    }
}

// ---------- flash attention: swapped MFMA + permlane P-transpose + K-split ----------
// grid (32 pairs, 25 q-tiles), block 256 = 4 waves: qgroup = wid>>1, khalf = wid&1.
__global__ __launch_bounds__(256) void attn_kernel(
    const unsigned short* __restrict__ qk, const unsigned short* __restrict__ vt,
    unsigned short* __restrict__ y_t)
{
    __shared__ float ocomb[2][64][36];   // partial O frags (padded stride 36)
    __shared__ float lcomb[2][2][16];    // partial row sums

    const int tid = threadIdx.x, wid = tid >> 6, lane = tid & 63;
    const int g = lane >> 4, cc = lane & 15;
    const int qgroup = wid >> 1, khalf = wid & 1;
    const int pair = blockIdx.x;
    const int q0 = blockIdx.y * 64 + qgroup * 32;
    const int n = pair & 3, b = pair >> 2;

    const unsigned short* qkb = qk + (size_t)pair * 1600 * 64;
    const unsigned short* vtb = vt + (size_t)pair * 64 * 1600;

    // Q as B-frags (col q = cc, contraction d = 8g..8g+7)
    bf16x8 bq0 = *(const bf16x8*)(qkb + (size_t)(q0 + cc) * 64 + 8 * g);
    bf16x8 bq1 = *(const bf16x8*)(qkb + (size_t)(q0 + 16 + cc) * 64 + 8 * g);

    const f32x4 fz = {0.f, 0.f, 0.f, 0.f};
    f32x4 o[2][4] = {{fz, fz, fz, fz}, {fz, fz, fz, fz}};
    float lrun[2] = {0.f, 0.f};

    const int kt_begin = khalf ? 13 : 0;
    const int kt_end   = khalf ? 25 : 13;

    // prefetch first tile of this half
    bf16x8 kf[4], vf[8];
    {
        const int kk0 = kt_begin * 64;
        #pragma unroll
        for (int f = 0; f < 4; ++f)
            kf[f] = *(const bf16x8*)(qkb + (size_t)(kk0 + 16 * f + cc) * 64 + 32 + 8 * g);
        #pragma unroll
        for (int f2 = 0; f2 < 4; ++f2)
            #pragma unroll
            for (int s2 = 0; s2 < 2; ++s2)
                vf[f2 * 2 + s2] = *(const bf16x8*)(vtb + (size_t)(16 * f2 + cc) * 1600 + kk0 + s2 * 32 + 8 * g);
    }

    for (int kt = kt_begin; kt < kt_end; ++kt) {
        const int kkn = (kt + 1 < kt_end) ? (kt + 1) * 64 : kt * 64;

        // ---- QK^T + exp + pack + permlane transpose (all in-register) ----
        unsigned pb_u[2][2][4];
        #pragma unroll
        for (int qf = 0; qf < 2; ++qf) {
            bf16x8 bq = qf ? bq1 : bq0;
            f32x4 s4[4];
            #pragma unroll
            for (int f = 0; f < 4; ++f)
                s4[f] = __builtin_amdgcn_mfma_f32_16x16x32_bf16(kf[f], bq, fz, 0, 0, 0);
            float sum = 0.f;
            unsigned c2[4][2];
            #pragma unroll
            for (int f = 0; f < 4; ++f) {
                float p0 = __expf(s4[f][0]), p1 = __expf(s4[f][1]);
                float p2 = __expf(s4[f][2]), p3 = __expf(s4[f][3]);
                sum += (p0 + p1) + (p2 + p3);
                c2[f][0] = pkbf(p0, p1);
                c2[f][1] = pkbf(p2, p3);
            }
            lrun[qf] += sum;
            // P^T B-frag build: per 32-t half, 2x permlane32_swap + 2x permlane16_swap
            #pragma unroll
            for (int s2 = 0; s2 < 2; ++s2) {
                const int fA = 2 * s2, fB = 2 * s2 + 1;
                u32x2 xy0 = __builtin_amdgcn_permlane32_swap(c2[fA][0], c2[fB][0], false, false);
                u32x2 xy1 = __builtin_amdgcn_permlane32_swap(c2[fA][1], c2[fB][1], false, false);
                u32x2 w02 = __builtin_amdgcn_permlane16_swap(xy0.x, xy0.y, false, false);
                u32x2 w13 = __builtin_amdgcn_permlane16_swap(xy1.x, xy1.y, false, false);
                pb_u[qf][s2][0] = w02.x;
                pb_u[qf][s2][1] = w13.x;
                pb_u[qf][s2][2] = w02.y;
                pb_u[qf][s2][3] = w13.y;
            }
        }

        // ---- prefetch next K (covered by PV) ----
        #pragma unroll
        for (int f = 0; f < 4; ++f)
            kf[f] = *(const bf16x8*)(qkb + (size_t)(kkn + 16 * f + cc) * 64 + 32 + 8 * g);

        // ---- PV: O^T += mfma(V^T_afrag, P^T_bfrag) ----
        #pragma unroll
        for (int qf = 0; qf < 2; ++qf) {
            #pragma unroll
            for (int s2 = 0; s2 < 2; ++s2) {
                union { unsigned u[4]; bf16x8 v; } pb;
                #pragma unroll
                for (int j = 0; j < 4; ++j) pb.u[j] = pb_u[qf][s2][j];
                #pragma unroll
                for (int f2 = 0; f2 < 4; ++f2)
                    o[qf][f2] = __builtin_amdgcn_mfma_f32_16x16x32_bf16(vf[f2 * 2 + s2], pb.v, o[qf][f2], 0, 0, 0);
            }
        }

        // ---- prefetch next V (covered by next QK + softmax) ----
        #pragma unroll
        for (int f2 = 0; f2 < 4; ++f2)
            #pragma unroll
            for (int s2 = 0; s2 < 2; ++s2)
                vf[f2 * 2 + s2] = *(const bf16x8*)(vtb + (size_t)(16 * f2 + cc) * 1600 + kkn + s2 * 32 + 8 * g);
    }

    // ---- per-wave row-sum reduce (across the 4 g-slices) ----
    float vsum[2];
    #pragma unroll
    for (int qf = 0; qf < 2; ++qf) {
        float v = lrun[qf];
        v += __shfl_xor(v, 16, 64);
        v += __shfl_xor(v, 32, 64);
        vsum[qf] = v;
    }

    // ---- combine the two K-halves through LDS ----
    if (khalf == 1) {
        #pragma unroll
        for (int qf = 0; qf < 2; ++qf)
            #pragma unroll
            for (int f2 = 0; f2 < 4; ++f2)
                *(f32x4*)&ocomb[qgroup][lane][qf * 16 + f2 * 4] = o[qf][f2];
        if (lane < 16) {
            lcomb[qgroup][0][cc] = vsum[0];
            lcomb[qgroup][1][cc] = vsum[1];
        }
    }
    __syncthreads();
    if (khalf == 0) {
        #pragma unroll
        for (int qf = 0; qf < 2; ++qf) {
            float il = 1.f / (vsum[qf] + lcomb[qgroup][qf][cc]);
            unsigned short* yb = y_t + ((size_t)b * 1600 + q0 + qf * 16 + cc) * 256 + n * 64;
            #pragma unroll
            for (int f2 = 0; f2 < 4; ++f2) {
                f32x4 oh = *(const f32x4*)&ocomb[qgroup][lane][qf * 16 + f2 * 4];
                u16x4 st;
                #pragma unroll
                for (int r = 0; r < 4; ++r) st[r] = f2bf((o[qf][f2][r] + oh[r]) * il);
                *(u16x4*)(yb + 16 * f2 + 4 * g) = st;
            }
        }
    }
}

// ---------- y2 = y + BN(depthwise3x3(v)) ----------
__global__ __launch_bounds__(256) void dw_kernel(
    const unsigned short* __restrict__ vt, const unsigned short* __restrict__ y_t,
    unsigned short* __restrict__ y2t,
    const float* __restrict__ cw, const float* __restrict__ gg,
    const float* __restrict__ bet, const float* __restrict__ mm,
    const float* __restrict__ vv)
{
    const int tid = threadIdx.x;
    const int l = blockIdx.x * 64 + (tid & 63);
    const int c0 = blockIdx.y * 32 + (tid >> 6) * 8;
    const int b = blockIdx.z;
    const int n = c0 >> 6, d0 = c0 & 63;
    const int h = l / 40, w = l - h * 40;

    const unsigned short* vb = vt + ((size_t)(b * 4 + n) * 64 + d0) * 1600;
    const float* cwp = cw + c0 * 9;

    float s[8];
    #pragma unroll
    for (int i = 0; i < 8; ++i) s[i] = 0.f;
    #pragma unroll
    for (int kh = -1; kh <= 1; ++kh) {
        int hh = h + kh;
        if (hh < 0 || hh >= 40) continue;
        #pragma unroll
        for (int kw = -1; kw <= 1; ++kw) {
            int ww = w + kw;
            if (ww < 0 || ww >= 40) continue;
            int off = hh * 40 + ww;
            #pragma unroll
            for (int i = 0; i < 8; ++i)
                s[i] = fmaf(bf2f(vb[(size_t)i * 1600 + off]),
                            cwp[i * 9 + (kh + 1) * 3 + (kw + 1)], s[i]);
        }
    }
    u16x8 yv = *(const u16x8*)(y_t + ((size_t)b * 1600 + l) * 256 + c0);
    u16x8 out;
    #pragma unroll
    for (int i = 0; i < 8; ++i) {
        int c = c0 + i;
        float iv = gg[c] * rsqrtf(vv[c] + EPS);
        out[i] = f2bf(bf2f(yv[i]) + s[i] * iv + (bet[c] - mm[c] * iv));
    }
    *(u16x8*)(y2t + ((size_t)b * 1600 + l) * 256 + c0) = out;
}

// ---------- out = BN(cb2_w @ y2) via MFMA, fp32 output [b][o][l] ----------
__global__ __launch_bounds__(256) void out_gemm_kernel(
    const unsigned short* __restrict__ wcb, const unsigned short* __restrict__ y2t,
    const float* __restrict__ gg, const float* __restrict__ bet,
    const float* __restrict__ mm, const float* __restrict__ vv,
    float* __restrict__ out)
{
    const int tid = threadIdx.x, wid = tid >> 6, lane = tid & 63;
    const int g = lane >> 4, cc = lane & 15;
    const int l0 = blockIdx.x * 64;
    const int o_base = blockIdx.y * 64 + wid * 16;
    const int b = blockIdx.z;

    const unsigned short* wb = wcb + (size_t)(o_base + cc) * 256;
    const unsigned short* yb = y2t + ((size_t)b * 1600 + l0 + cc) * 256;

    const f32x4 fzero = {0.f, 0.f, 0.f, 0.f};
    f32x4 acc[4] = {fzero, fzero, fzero, fzero};
    #pragma unroll 4
    for (int kk = 0; kk < 256; kk += 32) {
        bf16x8 af = *(const bf16x8*)(wb + kk + 8 * g);
        #pragma unroll
        for (int f = 0; f < 4; ++f) {
            bf16x8 bfr = *(const bf16x8*)(yb + (size_t)f * 16 * 256 + kk + 8 * g);
            acc[f] = __builtin_amdgcn_mfma_f32_16x16x32_bf16(af, bfr, acc[f], 0, 0, 0);
        }
    }
    #pragma unroll
    for (int r = 0; r < 4; ++r) {
        int oc = o_base + 4 * g + r;
        float iv = gg[oc] * rsqrtf(vv[oc] + EPS);
        float bs = bet[oc] - mm[oc] * iv;
        #pragma unroll
        for (int f = 0; f < 4; ++f)
            out[((size_t)b * 256 + oc) * 1600 + l0 + 16 * f + cc] = acc[f][r] * iv + bs;
    }
}

extern "C" void kernel_launch(void* const* d_in, const int* in_sizes, int n_in,
                              void* d_out, int out_size, void* d_ws, size_t ws_size,
                              hipStream_t stream) {
    const float* x     = (const float*)d_in[0];
    const float* qkv_w = (const float*)d_in[1];
    const float* qkv_g = (const float*)d_in[2];
    const float* qkv_b = (const float*)d_in[3];
    const float* qkv_m = (const float*)d_in[4];
    const float* qkv_v = (const float*)d_in[5];
    const float* cb1_w = (const float*)d_in[6];
    const float* cb1_g = (const float*)d_in[7];
    const float* cb1_b = (const float*)d_in[8];
    const float* cb1_m = (const float*)d_in[9];
    const float* cb1_v = (const float*)d_in[10];
    const float* cb2_w = (const float*)d_in[11];
    const float* cb2_g = (const float*)d_in[12];
    const float* cb2_b = (const float*)d_in[13];
    const float* cb2_m = (const float*)d_in[14];
    const float* cb2_v = (const float*)d_in[15];
    float* out = (float*)d_out;

    unsigned short* ws16 = (unsigned short*)d_ws;
    const size_t N16 = 3276800;                 // 8*1600*256
    unsigned short* xt  = ws16;
    unsigned short* qk  = ws16 + N16;           // [b][n][l][64] (q|k)
    unsigned short* vt  = ws16 + 2 * N16;       // [b][n][d][l]
    unsigned short* y_t = ws16 + 3 * N16;       // [b][l][256]
    unsigned short* y2t = ws16 + 4 * N16;       // [b][l][256]
    unsigned short* wqb = ws16 + 5 * N16;       // 512*256
    unsigned short* wcb = wqb + 131072;         // 256*256

    convw_kernel<<<dim3(192), 256, 0, stream>>>(qkv_w, cb2_w, wqb, wcb);
    convx_kernel<<<dim3(25, 4, 8), 256, 0, stream>>>(x, xt);
    qkv_gemm_kernel<<<dim3(25, 8, 8), 256, 0, stream>>>(wqb, xt, qkv_g, qkv_b, qkv_m, qkv_v, qk, vt);
    attn_kernel<<<dim3(32, 25), 256, 0, stream>>>(qk, vt, y_t);
    dw_kernel<<<dim3(25, 8, 8), 256, 0, stream>>>(vt, y_t, y2t, cb1_w, cb1_g, cb1_b, cb1_m, cb1_v);
    out_gemm_kernel<<<dim3(25, 4, 8), 256, 0, stream>>>(wcb, y2t, cb2_g, cb2_b, cb2_m, cb2_v, out);
}

// Round 6
// 157.901 us; speedup vs baseline: 1.0205x; 1.0205x over previous
//
#include <hip/hip_runtime.h>
#include <hip/hip_bf16.h>

#define EPS 1e-3f
// 1/sqrt(32) * log2(e): scores come out of QK^T already in log2-space
#define QSC_LOG2E 0.2550348653f

typedef __attribute__((ext_vector_type(8))) short bf16x8;
typedef __attribute__((ext_vector_type(4))) float f32x4;
typedef __attribute__((ext_vector_type(4))) unsigned short u16x4;
typedef __attribute__((ext_vector_type(8))) unsigned short u16x8;
typedef __attribute__((ext_vector_type(2))) unsigned int u32x2;

__device__ __forceinline__ unsigned short f2bf(float f) {
    union { float f; unsigned u; } v; v.f = f;
    unsigned r = v.u + 0x7FFFu + ((v.u >> 16) & 1u);
    return (unsigned short)(r >> 16);
}
__device__ __forceinline__ float bf2f(unsigned short h) {
    union { unsigned u; float f; } v; v.u = ((unsigned)h) << 16;
    return v.f;
}
__device__ __forceinline__ unsigned pkbf(float lo, float hi) {
    float2 t; t.x = lo; t.y = hi;
    __hip_bfloat162 h = __float22bfloat162_rn(t);
    union { __hip_bfloat162 h; unsigned u; } c; c.h = h;
    return c.u;
}

// ---------- convert both weight matrices to bf16 ----------
__global__ __launch_bounds__(256) void convw_kernel(
    const float* __restrict__ wq, const float* __restrict__ wc,
    unsigned short* __restrict__ wqb, unsigned short* __restrict__ wcb)
{
    int i = (blockIdx.x * 256 + threadIdx.x) * 4;
    const float* src; unsigned short* dst; int off;
    if (i < 131072) { src = wq; dst = wqb; off = i; }
    else            { src = wc; dst = wcb; off = i - 131072; }
    f32x4 v = *(const f32x4*)(src + off);
    u16x4 o;
    #pragma unroll
    for (int j = 0; j < 4; ++j) o[j] = f2bf(v[j]);
    *(u16x4*)(dst + off) = o;
}

// ---------- x [b][c][l] f32 -> xt [b][l][c] bf16 (LDS tile transpose) ----------
__global__ __launch_bounds__(256) void convx_kernel(
    const float* __restrict__ x, unsigned short* __restrict__ xt)
{
    __shared__ float t[64][65];
    int l0 = blockIdx.x * 64, c0 = blockIdx.y * 64, b = blockIdx.z;
    const float* xb = x + ((size_t)b * 256 + c0) * 1600 + l0;
    int tid = threadIdx.x;
    #pragma unroll
    for (int p = 0; p < 4; ++p) {
        int row = p * 16 + (tid >> 4);
        int col = (tid & 15) * 4;
        f32x4 v = *(const f32x4*)(xb + (size_t)row * 1600 + col);
        #pragma unroll
        for (int j = 0; j < 4; ++j) t[row][col + j] = v[j];
    }
    __syncthreads();
    int l = tid >> 2, cs = tid & 3;
    u16x8 o0, o1;
    #pragma unroll
    for (int i = 0; i < 8; ++i) o0[i] = f2bf(t[cs * 16 + i][l]);
    #pragma unroll
    for (int i = 0; i < 8; ++i) o1[i] = f2bf(t[cs * 16 + 8 + i][l]);
    unsigned short* dst = xt + ((size_t)b * 1600 + l0 + l) * 256 + c0 + cs * 16;
    *(u16x8*)dst = o0;
    *(u16x8*)(dst + 8) = o1;
}

// ---------- qkv = BN(qkv_w @ x) via MFMA; writes qk [b][n][l][64], vt [b][n][d][l] ----------
__global__ __launch_bounds__(256) void qkv_gemm_kernel(
    const unsigned short* __restrict__ wqb, const unsigned short* __restrict__ xt,
    const float* __restrict__ gg, const float* __restrict__ bet,
    const float* __restrict__ mm, const float* __restrict__ vv,
    unsigned short* __restrict__ qk, unsigned short* __restrict__ vt)
{
    const int tid = threadIdx.x, wid = tid >> 6, lane = tid & 63;
    const int g = lane >> 4, cc = lane & 15;
    const int l0 = blockIdx.x * 64;
    const int by = blockIdx.y;
    const int b  = blockIdx.z;
    const int o_base = by * 64 + wid * 16;

    const unsigned short* wb = wqb + (size_t)(o_base + cc) * 256;
    const unsigned short* xb = xt + ((size_t)b * 1600 + l0 + cc) * 256;

    const f32x4 fzero = {0.f, 0.f, 0.f, 0.f};
    f32x4 acc[4] = {fzero, fzero, fzero, fzero};
    #pragma unroll 4
    for (int kk = 0; kk < 256; kk += 32) {
        bf16x8 af = *(const bf16x8*)(wb + kk + 8 * g);
        #pragma unroll
        for (int f = 0; f < 4; ++f) {
            bf16x8 bfr = *(const bf16x8*)(xb + (size_t)f * 16 * 256 + kk + 8 * g);
            acc[f] = __builtin_amdgcn_mfma_f32_16x16x32_bf16(af, bfr, acc[f], 0, 0, 0);
        }
    }

    const int head = by >> 1;
    float inv[4], bias[4];
    #pragma unroll
    for (int r = 0; r < 4; ++r) {
        int oc = o_base + 4 * g + r;
        float iv = gg[oc] * rsqrtf(vv[oc] + EPS);
        float bs = bet[oc] - mm[oc] * iv;
        if ((oc & 127) < 32) { iv *= QSC_LOG2E; bs *= QSC_LOG2E; }  // q rows: fold scale*log2e
        inv[r] = iv; bias[r] = bs;
    }

    if (!(by & 1)) {
        unsigned short* dst = qk + ((size_t)(b * 4 + head) * 1600) * 64;
        #pragma unroll
        for (int f = 0; f < 4; ++f) {
            int l = l0 + 16 * f + cc;
            u16x4 pk;
            #pragma unroll
            for (int r = 0; r < 4; ++r) pk[r] = f2bf(acc[f][r] * inv[r] + bias[r]);
            *(u16x4*)(dst + (size_t)l * 64 + wid * 16 + 4 * g) = pk;
        }
    } else {
        unsigned short* dst = vt + ((size_t)(b * 4 + head) * 64) * 1600;
        #pragma unroll
        for (int f = 0; f < 4; ++f) {
            int l = l0 + 16 * f + cc;
            #pragma unroll
            for (int r = 0; r < 4; ++r) {
                int d = wid * 16 + 4 * g + r;
                dst[(size_t)d * 1600 + l] = f2bf(acc[f][r] * inv[r] + bias[r]);
            }
        }
    }
}

// ---------- flash attention: 4-way K-split, 32 q per block, permlane transpose ----------
// grid (32 pairs, 50 q-groups), block 256 = 4 waves; wave w owns K-quarter w.
__global__ __launch_bounds__(256) void attn_kernel(
    const unsigned short* __restrict__ qk, const unsigned short* __restrict__ vt,
    unsigned short* __restrict__ y_t)
{
    __shared__ float ocomb[3][64][33];   // partial O from waves 1..3 (pad 33: 2-way free)
    __shared__ float lcomb[3][2][16];    // partial row sums

    const int tid = threadIdx.x, wid = tid >> 6, lane = tid & 63;
    const int g = lane >> 4, cc = lane & 15;
    const int pair = blockIdx.x;
    const int q0 = blockIdx.y * 32;
    const int n = pair & 3, b = pair >> 2;

    const unsigned short* qkb = qk + (size_t)pair * 1600 * 64;
    const unsigned short* vtb = vt + (size_t)pair * 64 * 1600;

    // Q as B-frags (col q = cc, contraction d = 8g..8g+7)
    bf16x8 bq0 = *(const bf16x8*)(qkb + (size_t)(q0 + cc) * 64 + 8 * g);
    bf16x8 bq1 = *(const bf16x8*)(qkb + (size_t)(q0 + 16 + cc) * 64 + 8 * g);

    const f32x4 fz = {0.f, 0.f, 0.f, 0.f};
    f32x4 o[2][4] = {{fz, fz, fz, fz}, {fz, fz, fz, fz}};
    float lrun[2] = {0.f, 0.f};

    // K-quarters {6,6,6,7}; wave 0 (epilogue owner) gets 6
    const int kt_begin = 6 * wid;
    const int kt_end   = (wid == 3) ? 25 : (6 * wid + 6);

    bf16x8 kf[4], vf[8];
    {
        const int kk0 = kt_begin * 64;
        #pragma unroll
        for (int f = 0; f < 4; ++f)
            kf[f] = *(const bf16x8*)(qkb + (size_t)(kk0 + 16 * f + cc) * 64 + 32 + 8 * g);
        #pragma unroll
        for (int f2 = 0; f2 < 4; ++f2)
            #pragma unroll
            for (int s2 = 0; s2 < 2; ++s2)
                vf[f2 * 2 + s2] = *(const bf16x8*)(vtb + (size_t)(16 * f2 + cc) * 1600 + kk0 + s2 * 32 + 8 * g);
    }

    for (int kt = kt_begin; kt < kt_end; ++kt) {
        const int kkn = (kt + 1 < kt_end) ? (kt + 1) * 64 : kt * 64;

        // ---- QK^T + exp2 + pack + permlane transpose (all in-register) ----
        unsigned pb_u[2][2][4];
        #pragma unroll
        for (int qf = 0; qf < 2; ++qf) {
            bf16x8 bq = qf ? bq1 : bq0;
            f32x4 s4[4];
            __builtin_amdgcn_s_setprio(1);
            #pragma unroll
            for (int f = 0; f < 4; ++f)
                s4[f] = __builtin_amdgcn_mfma_f32_16x16x32_bf16(kf[f], bq, fz, 0, 0, 0);
            __builtin_amdgcn_s_setprio(0);
            float sum = 0.f;
            unsigned c2[4][2];
            #pragma unroll
            for (int f = 0; f < 4; ++f) {
                float p0 = exp2f(s4[f][0]), p1 = exp2f(s4[f][1]);
                float p2 = exp2f(s4[f][2]), p3 = exp2f(s4[f][3]);
                sum += (p0 + p1) + (p2 + p3);
                c2[f][0] = pkbf(p0, p1);
                c2[f][1] = pkbf(p2, p3);
            }
            lrun[qf] += sum;
            #pragma unroll
            for (int s2 = 0; s2 < 2; ++s2) {
                const int fA = 2 * s2, fB = 2 * s2 + 1;
                u32x2 xy0 = __builtin_amdgcn_permlane32_swap(c2[fA][0], c2[fB][0], false, false);
                u32x2 xy1 = __builtin_amdgcn_permlane32_swap(c2[fA][1], c2[fB][1], false, false);
                u32x2 w02 = __builtin_amdgcn_permlane16_swap(xy0.x, xy0.y, false, false);
                u32x2 w13 = __builtin_amdgcn_permlane16_swap(xy1.x, xy1.y, false, false);
                pb_u[qf][s2][0] = w02.x;
                pb_u[qf][s2][1] = w13.x;
                pb_u[qf][s2][2] = w02.y;
                pb_u[qf][s2][3] = w13.y;
            }
        }

        // ---- prefetch next K (covered by PV) ----
        #pragma unroll
        for (int f = 0; f < 4; ++f)
            kf[f] = *(const bf16x8*)(qkb + (size_t)(kkn + 16 * f + cc) * 64 + 32 + 8 * g);

        // ---- PV: O^T += mfma(V^T_afrag, P^T_bfrag) ----
        __builtin_amdgcn_s_setprio(1);
        #pragma unroll
        for (int qf = 0; qf < 2; ++qf) {
            #pragma unroll
            for (int s2 = 0; s2 < 2; ++s2) {
                union { unsigned u[4]; bf16x8 v; } pb;
                #pragma unroll
                for (int j = 0; j < 4; ++j) pb.u[j] = pb_u[qf][s2][j];
                #pragma unroll
                for (int f2 = 0; f2 < 4; ++f2)
                    o[qf][f2] = __builtin_amdgcn_mfma_f32_16x16x32_bf16(vf[f2 * 2 + s2], pb.v, o[qf][f2], 0, 0, 0);
            }
        }
        __builtin_amdgcn_s_setprio(0);

        // ---- prefetch next V (covered by next QK + softmax) ----
        #pragma unroll
        for (int f2 = 0; f2 < 4; ++f2)
            #pragma unroll
            for (int s2 = 0; s2 < 2; ++s2)
                vf[f2 * 2 + s2] = *(const bf16x8*)(vtb + (size_t)(16 * f2 + cc) * 1600 + kkn + s2 * 32 + 8 * g);
    }

    // ---- per-wave row-sum reduce (across the 4 g-slices) ----
    float vsum[2];
    #pragma unroll
    for (int qf = 0; qf < 2; ++qf) {
        float v = lrun[qf];
        v += __shfl_xor(v, 16, 64);
        v += __shfl_xor(v, 32, 64);
        vsum[qf] = v;
    }

    // ---- combine the four K-quarters through LDS ----
    if (wid != 0) {
        #pragma unroll
        for (int qf = 0; qf < 2; ++qf)
            #pragma unroll
            for (int f2 = 0; f2 < 4; ++f2)
                *(f32x4*)&ocomb[wid - 1][lane][qf * 16 + f2 * 4] = o[qf][f2];
        if (lane < 16) {
            lcomb[wid - 1][0][cc] = vsum[0];
            lcomb[wid - 1][1][cc] = vsum[1];
        }
    }
    __syncthreads();
    if (wid == 0) {
        #pragma unroll
        for (int qf = 0; qf < 2; ++qf) {
            float tot = vsum[qf] + lcomb[0][qf][cc] + lcomb[1][qf][cc] + lcomb[2][qf][cc];
            float il = 1.f / tot;
            unsigned short* yb = y_t + ((size_t)b * 1600 + q0 + qf * 16 + cc) * 256 + n * 64;
            #pragma unroll
            for (int f2 = 0; f2 < 4; ++f2) {
                f32x4 oh = o[qf][f2];
                #pragma unroll
                for (int j = 0; j < 3; ++j)
                    oh += *(const f32x4*)&ocomb[j][lane][qf * 16 + f2 * 4];
                u16x4 st;
                #pragma unroll
                for (int r = 0; r < 4; ++r) st[r] = f2bf(oh[r] * il);
                *(u16x4*)(yb + 16 * f2 + 4 * g) = st;
            }
        }
    }
}

// ---------- y2 = y + BN(depthwise3x3(v)) ----------
__global__ __launch_bounds__(256) void dw_kernel(
    const unsigned short* __restrict__ vt, const unsigned short* __restrict__ y_t,
    unsigned short* __restrict__ y2t,
    const float* __restrict__ cw, const float* __restrict__ gg,
    const float* __restrict__ bet, const float* __restrict__ mm,
    const float* __restrict__ vv)
{
    const int tid = threadIdx.x;
    const int l = blockIdx.x * 64 + (tid & 63);
    const int c0 = blockIdx.y * 32 + (tid >> 6) * 8;
    const int b = blockIdx.z;
    const int n = c0 >> 6, d0 = c0 & 63;
    const int h = l / 40, w = l - h * 40;

    const unsigned short* vb = vt + ((size_t)(b * 4 + n) * 64 + d0) * 1600;
    const float* cwp = cw + c0 * 9;

    float s[8];
    #pragma unroll
    for (int i = 0; i < 8; ++i) s[i] = 0.f;
    #pragma unroll
    for (int kh = -1; kh <= 1; ++kh) {
        int hh = h + kh;
        if (hh < 0 || hh >= 40) continue;
        #pragma unroll
        for (int kw = -1; kw <= 1; ++kw) {
            int ww = w + kw;
            if (ww < 0 || ww >= 40) continue;
            int off = hh * 40 + ww;
            #pragma unroll
            for (int i = 0; i < 8; ++i)
                s[i] = fmaf(bf2f(vb[(size_t)i * 1600 + off]),
                            cwp[i * 9 + (kh + 1) * 3 + (kw + 1)], s[i]);
        }
    }
    u16x8 yv = *(const u16x8*)(y_t + ((size_t)b * 1600 + l) * 256 + c0);
    u16x8 out;
    #pragma unroll
    for (int i = 0; i < 8; ++i) {
        int c = c0 + i;
        float iv = gg[c] * rsqrtf(vv[c] + EPS);
        out[i] = f2bf(bf2f(yv[i]) + s[i] * iv + (bet[c] - mm[c] * iv));
    }
    *(u16x8*)(y2t + ((size_t)b * 1600 + l) * 256 + c0) = out;
}

// ---------- out = BN(cb2_w @ y2) via MFMA, fp32 output [b][o][l] ----------
__global__ __launch_bounds__(256) void out_gemm_kernel(
    const unsigned short* __restrict__ wcb, const unsigned short* __restrict__ y2t,
    const float* __restrict__ gg, const float* __restrict__ bet,
    const float* __restrict__ mm, const float* __restrict__ vv,
    float* __restrict__ out)
{
    const int tid = threadIdx.x, wid = tid >> 6, lane = tid & 63;
    const int g = lane >> 4, cc = lane & 15;
    const int l0 = blockIdx.x * 64;
    const int o_base = blockIdx.y * 64 + wid * 16;
    const int b = blockIdx.z;

    const unsigned short* wb = wcb + (size_t)(o_base + cc) * 256;
    const unsigned short* yb = y2t + ((size_t)b * 1600 + l0 + cc) * 256;

    const f32x4 fzero = {0.f, 0.f, 0.f, 0.f};
    f32x4 acc[4] = {fzero, fzero, fzero, fzero};
    #pragma unroll 4
    for (int kk = 0; kk < 256; kk += 32) {
        bf16x8 af = *(const bf16x8*)(wb + kk + 8 * g);
        #pragma unroll
        for (int f = 0; f < 4; ++f) {
            bf16x8 bfr = *(const bf16x8*)(yb + (size_t)f * 16 * 256 + kk + 8 * g);
            acc[f] = __builtin_amdgcn_mfma_f32_16x16x32_bf16(af, bfr, acc[f], 0, 0, 0);
        }
    }
    #pragma unroll
    for (int r = 0; r < 4; ++r) {
        int oc = o_base + 4 * g + r;
        float iv = gg[oc] * rsqrtf(vv[oc] + EPS);
        float bs = bet[oc] - mm[oc] * iv;
        #pragma unroll
        for (int f = 0; f < 4; ++f)
            out[((size_t)b * 256 + oc) * 1600 + l0 + 16 * f + cc] = acc[f][r] * iv + bs;
    }
}

extern "C" void kernel_launch(void* const* d_in, const int* in_sizes, int n_in,
                              void* d_out, int out_size, void* d_ws, size_t ws_size,
                              hipStream_t stream) {
    const float* x     = (const float*)d_in[0];
    const float* qkv_w = (const float*)d_in[1];
    const float* qkv_g = (const float*)d_in[2];
    const float* qkv_b = (const float*)d_in[3];
    const float* qkv_m = (const float*)d_in[4];
    const float* qkv_v = (const float*)d_in[5];
    const float* cb1_w = (const float*)d_in[6];
    const float* cb1_g = (const float*)d_in[7];
    const float* cb1_b = (const float*)d_in[8];
    const float* cb1_m = (const float*)d_in[9];
    const float* cb1_v = (const float*)d_in[10];
    const float* cb2_w = (const float*)d_in[11];
    const float* cb2_g = (const float*)d_in[12];
    const float* cb2_b = (const float*)d_in[13];
    const float* cb2_m = (const float*)d_in[14];
    const float* cb2_v = (const float*)d_in[15];
    float* out = (float*)d_out;

    unsigned short* ws16 = (unsigned short*)d_ws;
    const size_t N16 = 3276800;                 // 8*1600*256
    unsigned short* xt  = ws16;
    unsigned short* qk  = ws16 + N16;           // [b][n][l][64] (q|k)
    unsigned short* vt  = ws16 + 2 * N16;       // [b][n][d][l]
    unsigned short* y_t = ws16 + 3 * N16;       // [b][l][256]
    unsigned short* y2t = ws16 + 4 * N16;       // [b][l][256]
    unsigned short* wqb = ws16 + 5 * N16;       // 512*256
    unsigned short* wcb = wqb + 131072;         // 256*256

    convw_kernel<<<dim3(192), 256, 0, stream>>>(qkv_w, cb2_w, wqb, wcb);
    convx_kernel<<<dim3(25, 4, 8), 256, 0, stream>>>(x, xt);
    qkv_gemm_kernel<<<dim3(25, 8, 8), 256, 0, stream>>>(wqb, xt, qkv_g, qkv_b, qkv_m, qkv_v, qk, vt);
    attn_kernel<<<dim3(32, 50), 256, 0, stream>>>(qk, vt, y_t);
    dw_kernel<<<dim3(25, 8, 8), 256, 0, stream>>>(vt, y_t, y2t, cb1_w, cb1_g, cb1_b, cb1_m, cb1_v);
    out_gemm_kernel<<<dim3(25, 4, 8), 256, 0, stream>>>(wcb, y2t, cb2_g, cb2_b, cb2_m, cb2_v, out);
}

// Round 7
// 135.073 us; speedup vs baseline: 1.1930x; 1.1690x over previous
//
#include <hip/hip_runtime.h>
#include <hip/hip_bf16.h>

#define EPS 1e-3f
// 1/sqrt(32) * log2(e): scores come out of QK^T already in log2-space
#define QSC_LOG2E 0.2550348653f

typedef __attribute__((ext_vector_type(8))) short bf16x8;
typedef __attribute__((ext_vector_type(4))) float f32x4;
typedef __attribute__((ext_vector_type(4))) unsigned short u16x4;
typedef __attribute__((ext_vector_type(8))) unsigned short u16x8;
typedef __attribute__((ext_vector_type(2))) unsigned int u32x2;

typedef const __attribute__((address_space(1))) unsigned int g_u32;
typedef __attribute__((address_space(3))) unsigned int l_u32;

__device__ __forceinline__ unsigned short f2bf(float f) {
    union { float f; unsigned u; } v; v.f = f;
    unsigned r = v.u + 0x7FFFu + ((v.u >> 16) & 1u);
    return (unsigned short)(r >> 16);
}
__device__ __forceinline__ float bf2f(unsigned short h) {
    union { unsigned u; float f; } v; v.u = ((unsigned)h) << 16;
    return v.f;
}
__device__ __forceinline__ unsigned pkbf(float lo, float hi) {
    float2 t; t.x = lo; t.y = hi;
    __hip_bfloat162 h = __float22bfloat162_rn(t);
    union { __hip_bfloat162 h; unsigned u; } c; c.h = h;
    return c.u;
}

// ---------- convert both weight matrices to bf16 ----------
__global__ __launch_bounds__(256) void convw_kernel(
    const float* __restrict__ wq, const float* __restrict__ wc,
    unsigned short* __restrict__ wqb, unsigned short* __restrict__ wcb)
{
    int i = (blockIdx.x * 256 + threadIdx.x) * 4;
    const float* src; unsigned short* dst; int off;
    if (i < 131072) { src = wq; dst = wqb; off = i; }
    else            { src = wc; dst = wcb; off = i - 131072; }
    f32x4 v = *(const f32x4*)(src + off);
    u16x4 o;
    #pragma unroll
    for (int j = 0; j < 4; ++j) o[j] = f2bf(v[j]);
    *(u16x4*)(dst + off) = o;
}

// ---------- x [b][c][l] f32 -> xt [b][l][c] bf16 (LDS tile transpose) ----------
__global__ __launch_bounds__(256) void convx_kernel(
    const float* __restrict__ x, unsigned short* __restrict__ xt)
{
    __shared__ float t[64][65];
    int l0 = blockIdx.x * 64, c0 = blockIdx.y * 64, b = blockIdx.z;
    const float* xb = x + ((size_t)b * 256 + c0) * 1600 + l0;
    int tid = threadIdx.x;
    #pragma unroll
    for (int p = 0; p < 4; ++p) {
        int row = p * 16 + (tid >> 4);
        int col = (tid & 15) * 4;
        f32x4 v = *(const f32x4*)(xb + (size_t)row * 1600 + col);
        #pragma unroll
        for (int j = 0; j < 4; ++j) t[row][col + j] = v[j];
    }
    __syncthreads();
    int l = tid >> 2, cs = tid & 3;
    u16x8 o0, o1;
    #pragma unroll
    for (int i = 0; i < 8; ++i) o0[i] = f2bf(t[cs * 16 + i][l]);
    #pragma unroll
    for (int i = 0; i < 8; ++i) o1[i] = f2bf(t[cs * 16 + 8 + i][l]);
    unsigned short* dst = xt + ((size_t)b * 1600 + l0 + l) * 256 + c0 + cs * 16;
    *(u16x8*)dst = o0;
    *(u16x8*)(dst + 8) = o1;
}

// ---------- qkv = BN(qkv_w @ x) via MFMA; writes qk [b][n][l][64], vt [b][n][d][l] ----------
__global__ __launch_bounds__(256) void qkv_gemm_kernel(
    const unsigned short* __restrict__ wqb, const unsigned short* __restrict__ xt,
    const float* __restrict__ gg, const float* __restrict__ bet,
    const float* __restrict__ mm, const float* __restrict__ vv,
    unsigned short* __restrict__ qk, unsigned short* __restrict__ vt)
{
    const int tid = threadIdx.x, wid = tid >> 6, lane = tid & 63;
    const int g = lane >> 4, cc = lane & 15;
    const int l0 = blockIdx.x * 64;
    const int by = blockIdx.y;
    const int b  = blockIdx.z;
    const int o_base = by * 64 + wid * 16;

    const unsigned short* wb = wqb + (size_t)(o_base + cc) * 256;
    const unsigned short* xb = xt + ((size_t)b * 1600 + l0 + cc) * 256;

    const f32x4 fzero = {0.f, 0.f, 0.f, 0.f};
    f32x4 acc[4] = {fzero, fzero, fzero, fzero};
    #pragma unroll 4
    for (int kk = 0; kk < 256; kk += 32) {
        bf16x8 af = *(const bf16x8*)(wb + kk + 8 * g);
        #pragma unroll
        for (int f = 0; f < 4; ++f) {
            bf16x8 bfr = *(const bf16x8*)(xb + (size_t)f * 16 * 256 + kk + 8 * g);
            acc[f] = __builtin_amdgcn_mfma_f32_16x16x32_bf16(af, bfr, acc[f], 0, 0, 0);
        }
    }

    const int head = by >> 1;
    float inv[4], bias[4];
    #pragma unroll
    for (int r = 0; r < 4; ++r) {
        int oc = o_base + 4 * g + r;
        float iv = gg[oc] * rsqrtf(vv[oc] + EPS);
        float bs = bet[oc] - mm[oc] * iv;
        if ((oc & 127) < 32) { iv *= QSC_LOG2E; bs *= QSC_LOG2E; }  // q rows: fold scale*log2e
        inv[r] = iv; bias[r] = bs;
    }

    if (!(by & 1)) {
        unsigned short* dst = qk + ((size_t)(b * 4 + head) * 1600) * 64;
        #pragma unroll
        for (int f = 0; f < 4; ++f) {
            int l = l0 + 16 * f + cc;
            u16x4 pk;
            #pragma unroll
            for (int r = 0; r < 4; ++r) pk[r] = f2bf(acc[f][r] * inv[r] + bias[r]);
            *(u16x4*)(dst + (size_t)l * 64 + wid * 16 + 4 * g) = pk;
        }
    } else {
        unsigned short* dst = vt + ((size_t)(b * 4 + head) * 64) * 1600;
        #pragma unroll
        for (int f = 0; f < 4; ++f) {
            int l = l0 + 16 * f + cc;
            #pragma unroll
            for (int r = 0; r < 4; ++r) {
                int d = wid * 16 + 4 * g + r;
                dst[(size_t)d * 1600 + l] = f2bf(acc[f][r] * inv[r] + bias[r]);
            }
        }
    }
}

// ---------- flash attention: LDS-staged K/V (global_load_lds, dbuf, swizzle) ----------
// grid (32 pairs, 25 q-tiles), block 256 = 4 waves x 16 q = 64 q per block.
// Each wave owns the full K range for its 16 queries; waves share staged tiles.
__global__ __launch_bounds__(256) void attn_kernel(
    const unsigned short* __restrict__ qk, const unsigned short* __restrict__ vt,
    unsigned short* __restrict__ y_t)
{
    __shared__ __align__(16) unsigned short kbuf[2][64 * 32];  // [t][d], 64B rows, chunk^=(t&3)
    __shared__ __align__(16) unsigned short vbuf[2][64 * 64];  // [d][t], 128B rows, chunk^=(d&7)

    const int tid = threadIdx.x, wid = tid >> 6, lane = tid & 63;
    const int g = lane >> 4, cc = lane & 15;
    const int pair = blockIdx.x;
    const int q0 = blockIdx.y * 64 + wid * 16;
    const int n = pair & 3, b = pair >> 2;

    const unsigned short* qkb = qk + (size_t)pair * 1600 * 64;
    const unsigned short* vtb = vt + (size_t)pair * 64 * 1600;

    // Q as B-frag (col q = cc, contraction d = 8g..8g+7)
    bf16x8 bq = *(const bf16x8*)(qkb + (size_t)(q0 + cc) * 64 + 8 * g);

    // staging source pointers (per-lane, inverse-swizzled)
    const int kt_row = tid >> 2, kt_chk = tid & 3;
    const unsigned short* ksrc0 = qkb + (size_t)kt_row * 64 + 32 + (kt_chk ^ (kt_row & 3)) * 8;
    const int vd_row = tid >> 3, vd_chk = tid & 7;
    const unsigned short* vsrc0 = vtb + (size_t)vd_row * 1600 + (vd_chk ^ (vd_row & 7)) * 8;

    #define STAGE(bufi, kk0)                                                            \
        do {                                                                            \
            __builtin_amdgcn_global_load_lds(                                           \
                (g_u32*)(ksrc0 + (size_t)(kk0) * 64),                                   \
                (l_u32*)(&kbuf[bufi][wid * 512]), 16, 0, 0);                            \
            __builtin_amdgcn_global_load_lds(                                           \
                (g_u32*)(vsrc0 + (kk0)),                                                \
                (l_u32*)(&vbuf[bufi][wid * 512]), 16, 0, 0);                            \
            __builtin_amdgcn_global_load_lds(                                           \
                (g_u32*)(vsrc0 + (size_t)32 * 1600 + (kk0)),                            \
                (l_u32*)(&vbuf[bufi][2048 + wid * 512]), 16, 0, 0);                     \
        } while (0)

    STAGE(0, 0);
    __syncthreads();

    const f32x4 fz = {0.f, 0.f, 0.f, 0.f};
    f32x4 o[4] = {fz, fz, fz, fz};
    float lrun = 0.f;
    int cur = 0;

    for (int kt = 0; kt < 25; ++kt) {
        if (kt + 1 < 25) STAGE(cur ^ 1, (kt + 1) * 64);

        // ---- fragment reads from LDS (swizzled) ----
        bf16x8 kf[4], vf[8];
        #pragma unroll
        for (int f = 0; f < 4; ++f) {
            int t = 16 * f + cc;
            kf[f] = *(const bf16x8*)&kbuf[cur][t * 32 + (g ^ (t & 3)) * 8];
        }
        #pragma unroll
        for (int f2 = 0; f2 < 4; ++f2) {
            int d = 16 * f2 + cc;
            #pragma unroll
            for (int s2 = 0; s2 < 2; ++s2)
                vf[f2 * 2 + s2] = *(const bf16x8*)&vbuf[cur][d * 64 + (((4 * s2 + g) ^ (d & 7)) * 8)];
        }

        // ---- QK^T (S^T frag: rows t = 16f+4g+r, col q = cc) ----
        f32x4 s4[4];
        __builtin_amdgcn_s_setprio(1);
        #pragma unroll
        for (int f = 0; f < 4; ++f)
            s4[f] = __builtin_amdgcn_mfma_f32_16x16x32_bf16(kf[f], bq, fz, 0, 0, 0);
        __builtin_amdgcn_s_setprio(0);

        // ---- exp2 + pack + permlane transpose (in-register) ----
        float sum = 0.f;
        unsigned c2[4][2];
        #pragma unroll
        for (int f = 0; f < 4; ++f) {
            float p0 = exp2f(s4[f][0]), p1 = exp2f(s4[f][1]);
            float p2 = exp2f(s4[f][2]), p3 = exp2f(s4[f][3]);
            sum += (p0 + p1) + (p2 + p3);
            c2[f][0] = pkbf(p0, p1);
            c2[f][1] = pkbf(p2, p3);
        }
        lrun += sum;
        unsigned pb_u[2][4];
        #pragma unroll
        for (int s2 = 0; s2 < 2; ++s2) {
            const int fA = 2 * s2, fB = 2 * s2 + 1;
            u32x2 xy0 = __builtin_amdgcn_permlane32_swap(c2[fA][0], c2[fB][0], false, false);
            u32x2 xy1 = __builtin_amdgcn_permlane32_swap(c2[fA][1], c2[fB][1], false, false);
            u32x2 w02 = __builtin_amdgcn_permlane16_swap(xy0.x, xy0.y, false, false);
            u32x2 w13 = __builtin_amdgcn_permlane16_swap(xy1.x, xy1.y, false, false);
            pb_u[s2][0] = w02.x;
            pb_u[s2][1] = w13.x;
            pb_u[s2][2] = w02.y;
            pb_u[s2][3] = w13.y;
        }

        // ---- PV: O^T += mfma(V^T_afrag, P^T_bfrag) ----
        __builtin_amdgcn_s_setprio(1);
        #pragma unroll
        for (int s2 = 0; s2 < 2; ++s2) {
            union { unsigned u[4]; bf16x8 v; } pb;
            #pragma unroll
            for (int j = 0; j < 4; ++j) pb.u[j] = pb_u[s2][j];
            #pragma unroll
            for (int f2 = 0; f2 < 4; ++f2)
                o[f2] = __builtin_amdgcn_mfma_f32_16x16x32_bf16(vf[f2 * 2 + s2], pb.v, o[f2], 0, 0, 0);
        }
        __builtin_amdgcn_s_setprio(0);

        __syncthreads();   // drains staging vmcnt + protects dbuf reuse
        cur ^= 1;
    }
    #undef STAGE

    // ---- epilogue: lane-local normalizer, vectorized bf16 stores ----
    float v = lrun;
    v += __shfl_xor(v, 16, 64);
    v += __shfl_xor(v, 32, 64);
    float il = 1.f / v;
    unsigned short* yb = y_t + ((size_t)b * 1600 + q0 + cc) * 256 + n * 64;
    #pragma unroll
    for (int f2 = 0; f2 < 4; ++f2) {
        u16x4 st;
        #pragma unroll
        for (int r = 0; r < 4; ++r) st[r] = f2bf(o[f2][r] * il);
        *(u16x4*)(yb + 16 * f2 + 4 * g) = st;
    }
}

// ---------- y2 = y + BN(depthwise3x3(v)) ----------
__global__ __launch_bounds__(256) void dw_kernel(
    const unsigned short* __restrict__ vt, const unsigned short* __restrict__ y_t,
    unsigned short* __restrict__ y2t,
    const float* __restrict__ cw, const float* __restrict__ gg,
    const float* __restrict__ bet, const float* __restrict__ mm,
    const float* __restrict__ vv)
{
    const int tid = threadIdx.x;
    const int l = blockIdx.x * 64 + (tid & 63);
    const int c0 = blockIdx.y * 32 + (tid >> 6) * 8;
    const int b = blockIdx.z;
    const int n = c0 >> 6, d0 = c0 & 63;
    const int h = l / 40, w = l - h * 40;

    const unsigned short* vb = vt + ((size_t)(b * 4 + n) * 64 + d0) * 1600;
    const float* cwp = cw + c0 * 9;

    float s[8];
    #pragma unroll
    for (int i = 0; i < 8; ++i) s[i] = 0.f;
    #pragma unroll
    for (int kh = -1; kh <= 1; ++kh) {
        int hh = h + kh;
        if (hh < 0 || hh >= 40) continue;
        #pragma unroll
        for (int kw = -1; kw <= 1; ++kw) {
            int ww = w + kw;
            if (ww < 0 || ww >= 40) continue;
            int off = hh * 40 + ww;
            #pragma unroll
            for (int i = 0; i < 8; ++i)
                s[i] = fmaf(bf2f(vb[(size_t)i * 1600 + off]),
                            cwp[i * 9 + (kh + 1) * 3 + (kw + 1)], s[i]);
        }
    }
    u16x8 yv = *(const u16x8*)(y_t + ((size_t)b * 1600 + l) * 256 + c0);
    u16x8 out;
    #pragma unroll
    for (int i = 0; i < 8; ++i) {
        int c = c0 + i;
        float iv = gg[c] * rsqrtf(vv[c] + EPS);
        out[i] = f2bf(bf2f(yv[i]) + s[i] * iv + (bet[c] - mm[c] * iv));
    }
    *(u16x8*)(y2t + ((size_t)b * 1600 + l) * 256 + c0) = out;
}

// ---------- out = BN(cb2_w @ y2) via MFMA, fp32 output [b][o][l] ----------
__global__ __launch_bounds__(256) void out_gemm_kernel(
    const unsigned short* __restrict__ wcb, const unsigned short* __restrict__ y2t,
    const float* __restrict__ gg, const float* __restrict__ bet,
    const float* __restrict__ mm, const float* __restrict__ vv,
    float* __restrict__ out)
{
    const int tid = threadIdx.x, wid = tid >> 6, lane = tid & 63;
    const int g = lane >> 4, cc = lane & 15;
    const int l0 = blockIdx.x * 64;
    const int o_base = blockIdx.y * 64 + wid * 16;
    const int b = blockIdx.z;

    const unsigned short* wb = wcb + (size_t)(o_base + cc) * 256;
    const unsigned short* yb = y2t + ((size_t)b * 1600 + l0 + cc) * 256;

    const f32x4 fzero = {0.f, 0.f, 0.f, 0.f};
    f32x4 acc[4] = {fzero, fzero, fzero, fzero};
    #pragma unroll 4
    for (int kk = 0; kk < 256; kk += 32) {
        bf16x8 af = *(const bf16x8*)(wb + kk + 8 * g);
        #pragma unroll
        for (int f = 0; f < 4; ++f) {
            bf16x8 bfr = *(const bf16x8*)(yb + (size_t)f * 16 * 256 + kk + 8 * g);
            acc[f] = __builtin_amdgcn_mfma_f32_16x16x32_bf16(af, bfr, acc[f], 0, 0, 0);
        }
    }
    #pragma unroll
    for (int r = 0; r < 4; ++r) {
        int oc = o_base + 4 * g + r;
        float iv = gg[oc] * rsqrtf(vv[oc] + EPS);
        float bs = bet[oc] - mm[oc] * iv;
        #pragma unroll
        for (int f = 0; f < 4; ++f)
            out[((size_t)b * 256 + oc) * 1600 + l0 + 16 * f + cc] = acc[f][r] * iv + bs;
    }
}

extern "C" void kernel_launch(void* const* d_in, const int* in_sizes, int n_in,
                              void* d_out, int out_size, void* d_ws, size_t ws_size,
                              hipStream_t stream) {
    const float* x     = (const float*)d_in[0];
    const float* qkv_w = (const float*)d_in[1];
    const float* qkv_g = (const float*)d_in[2];
    const float* qkv_b = (const float*)d_in[3];
    const float* qkv_m = (const float*)d_in[4];
    const float* qkv_v = (const float*)d_in[5];
    const float* cb1_w = (const float*)d_in[6];
    const float* cb1_g = (const float*)d_in[7];
    const float* cb1_b = (const float*)d_in[8];
    const float* cb1_m = (const float*)d_in[9];
    const float* cb1_v = (const float*)d_in[10];
    const float* cb2_w = (const float*)d_in[11];
    const float* cb2_g = (const float*)d_in[12];
    const float* cb2_b = (const float*)d_in[13];
    const float* cb2_m = (const float*)d_in[14];
    const float* cb2_v = (const float*)d_in[15];
    float* out = (float*)d_out;

    unsigned short* ws16 = (unsigned short*)d_ws;
    const size_t N16 = 3276800;                 // 8*1600*256
    unsigned short* xt  = ws16;
    unsigned short* qk  = ws16 + N16;           // [b][n][l][64] (q|k)
    unsigned short* vt  = ws16 + 2 * N16;       // [b][n][d][l]
    unsigned short* y_t = ws16 + 3 * N16;       // [b][l][256]
    unsigned short* y2t = ws16 + 4 * N16;       // [b][l][256]
    unsigned short* wqb = ws16 + 5 * N16;       // 512*256
    unsigned short* wcb = wqb + 131072;         // 256*256

    convw_kernel<<<dim3(192), 256, 0, stream>>>(qkv_w, cb2_w, wqb, wcb);
    convx_kernel<<<dim3(25, 4, 8), 256, 0, stream>>>(x, xt);
    qkv_gemm_kernel<<<dim3(25, 8, 8), 256, 0, stream>>>(wqb, xt, qkv_g, qkv_b, qkv_m, qkv_v, qk, vt);
    attn_kernel<<<dim3(32, 25), 256, 0, stream>>>(qk, vt, y_t);
    dw_kernel<<<dim3(25, 8, 8), 256, 0, stream>>>(vt, y_t, y2t, cb1_w, cb1_g, cb1_b, cb1_m, cb1_v);
    out_gemm_kernel<<<dim3(25, 4, 8), 256, 0, stream>>>(wcb, y2t, cb2_g, cb2_b, cb2_m, cb2_v, out);
}

// Round 8
// 126.498 us; speedup vs baseline: 1.2739x; 1.0678x over previous
//
#include <hip/hip_runtime.h>
#include <hip/hip_bf16.h>

#define EPS 1e-3f
// 1/sqrt(32) * log2(e): scores come out of QK^T already in log2-space
#define QSC_LOG2E 0.2550348653f

typedef __attribute__((ext_vector_type(8))) short bf16x8;
typedef __attribute__((ext_vector_type(4))) float f32x4;
typedef __attribute__((ext_vector_type(4))) unsigned short u16x4;
typedef __attribute__((ext_vector_type(8))) unsigned short u16x8;
typedef __attribute__((ext_vector_type(2))) unsigned int u32x2;

typedef const __attribute__((address_space(1))) unsigned int g_u32;
typedef __attribute__((address_space(3))) unsigned int l_u32;

__device__ __forceinline__ unsigned short f2bf(float f) {
    union { float f; unsigned u; } v; v.f = f;
    unsigned r = v.u + 0x7FFFu + ((v.u >> 16) & 1u);
    return (unsigned short)(r >> 16);
}
__device__ __forceinline__ float bf2f(unsigned short h) {
    union { unsigned u; float f; } v; v.u = ((unsigned)h) << 16;
    return v.f;
}
__device__ __forceinline__ unsigned pkbf(float lo, float hi) {
    float2 t; t.x = lo; t.y = hi;
    __hip_bfloat162 h = __float22bfloat162_rn(t);
    union { __hip_bfloat162 h; unsigned u; } c; c.h = h;
    return c.u;
}

// ---------- convert both weight matrices to bf16 ----------
__global__ __launch_bounds__(256) void convw_kernel(
    const float* __restrict__ wq, const float* __restrict__ wc,
    unsigned short* __restrict__ wqb, unsigned short* __restrict__ wcb)
{
    int i = (blockIdx.x * 256 + threadIdx.x) * 4;
    const float* src; unsigned short* dst; int off;
    if (i < 131072) { src = wq; dst = wqb; off = i; }
    else            { src = wc; dst = wcb; off = i - 131072; }
    f32x4 v = *(const f32x4*)(src + off);
    u16x4 o;
    #pragma unroll
    for (int j = 0; j < 4; ++j) o[j] = f2bf(v[j]);
    *(u16x4*)(dst + off) = o;
}

// ---------- x [b][c][l] f32 -> xt [gl][c] bf16 (LDS tile transpose) ----------
__global__ __launch_bounds__(256) void convx_kernel(
    const float* __restrict__ x, unsigned short* __restrict__ xt)
{
    __shared__ float t[64][65];
    int l0 = blockIdx.x * 64, c0 = blockIdx.y * 64, b = blockIdx.z;
    const float* xb = x + ((size_t)b * 256 + c0) * 1600 + l0;
    int tid = threadIdx.x;
    #pragma unroll
    for (int p = 0; p < 4; ++p) {
        int row = p * 16 + (tid >> 4);
        int col = (tid & 15) * 4;
        f32x4 v = *(const f32x4*)(xb + (size_t)row * 1600 + col);
        #pragma unroll
        for (int j = 0; j < 4; ++j) t[row][col + j] = v[j];
    }
    __syncthreads();
    int l = tid >> 2, cs = tid & 3;
    u16x8 o0, o1;
    #pragma unroll
    for (int i = 0; i < 8; ++i) o0[i] = f2bf(t[cs * 16 + i][l]);
    #pragma unroll
    for (int i = 0; i < 8; ++i) o1[i] = f2bf(t[cs * 16 + 8 + i][l]);
    unsigned short* dst = xt + ((size_t)b * 1600 + l0 + l) * 256 + c0 + cs * 16;
    *(u16x8*)dst = o0;
    *(u16x8*)(dst + 8) = o1;
}

// ---------- qkv = BN(qkv_w @ x) via MFMA, 32o x 64l per wave ----------
// grid (100, 8): block covers o in [by*64, by*64+64), gl in [bx*128, bx*128+128)
// writes qk [pair][l][64], vt [pair][d][l], v2 [gl][256] (v in channel-major)
__global__ __launch_bounds__(256) void qkv_gemm_kernel(
    const unsigned short* __restrict__ wqb, const unsigned short* __restrict__ xt,
    const float* __restrict__ gg, const float* __restrict__ bet,
    const float* __restrict__ mm, const float* __restrict__ vv,
    unsigned short* __restrict__ qk, unsigned short* __restrict__ vt,
    unsigned short* __restrict__ v2)
{
    const int tid = threadIdx.x, wid = tid >> 6, lane = tid & 63;
    const int g = lane >> 4, cc = lane & 15;
    const int gl0 = blockIdx.x * 128 + (wid & 1) * 64;
    const int o_base = blockIdx.y * 64 + (wid >> 1) * 32;

    const unsigned short* wb0 = wqb + (size_t)(o_base + cc) * 256;
    const unsigned short* wb1 = wqb + (size_t)(o_base + 16 + cc) * 256;
    const unsigned short* xb  = xt + (size_t)(gl0 + cc) * 256;

    const f32x4 fz = {0.f, 0.f, 0.f, 0.f};
    f32x4 acc[2][4] = {{fz, fz, fz, fz}, {fz, fz, fz, fz}};
    #pragma unroll 4
    for (int kk = 0; kk < 256; kk += 32) {
        bf16x8 a0 = *(const bf16x8*)(wb0 + kk + 8 * g);
        bf16x8 a1 = *(const bf16x8*)(wb1 + kk + 8 * g);
        #pragma unroll
        for (int f = 0; f < 4; ++f) {
            bf16x8 bfr = *(const bf16x8*)(xb + (size_t)f * 16 * 256 + kk + 8 * g);
            acc[0][f] = __builtin_amdgcn_mfma_f32_16x16x32_bf16(a0, bfr, acc[0][f], 0, 0, 0);
            acc[1][f] = __builtin_amdgcn_mfma_f32_16x16x32_bf16(a1, bfr, acc[1][f], 0, 0, 0);
        }
    }

    const int head = blockIdx.y >> 1;
    const bool is_v = blockIdx.y & 1;
    float inv[2][4], bias[2][4];
    #pragma unroll
    for (int i = 0; i < 2; ++i) {
        #pragma unroll
        for (int r = 0; r < 4; ++r) {
            int oc = o_base + 16 * i + 4 * g + r;
            float iv = gg[oc] * rsqrtf(vv[oc] + EPS);
            float bs = bet[oc] - mm[oc] * iv;
            if ((oc & 127) < 32) { iv *= QSC_LOG2E; bs *= QSC_LOG2E; }
            inv[i][r] = iv; bias[i][r] = bs;
        }
    }

    #pragma unroll
    for (int f = 0; f < 4; ++f) {
        int gl = gl0 + 16 * f + cc;
        int b  = gl / 1600;
        int ll = gl - b * 1600;
        if (!is_v) {
            unsigned short* dst = qk + ((size_t)(b * 4 + head) * 1600 + ll) * 64;
            #pragma unroll
            for (int i = 0; i < 2; ++i) {
                u16x4 pk;
                #pragma unroll
                for (int r = 0; r < 4; ++r) pk[r] = f2bf(acc[i][f][r] * inv[i][r] + bias[i][r]);
                *(u16x4*)(dst + (o_base & 63) + 16 * i + 4 * g) = pk;
            }
        } else {
            const int d_base = (o_base & 63);
            unsigned short* vdst = vt + ((size_t)(b * 4 + head) * 64) * 1600 + ll;
            unsigned short* v2dst = v2 + (size_t)gl * 256 + head * 64 + d_base;
            #pragma unroll
            for (int i = 0; i < 2; ++i) {
                u16x4 pk;
                #pragma unroll
                for (int r = 0; r < 4; ++r) {
                    unsigned short h = f2bf(acc[i][f][r] * inv[i][r] + bias[i][r]);
                    pk[r] = h;
                    vdst[(size_t)(d_base + 16 * i + 4 * g + r) * 1600] = h;
                }
                *(u16x4*)(v2dst + 16 * i + 4 * g) = pk;
            }
        }
    }
}

// ---------- flash attention: LDS-staged K/V + MFMA row-sum ----------
// grid (32 pairs, 25 q-tiles), block 256 = 4 waves x 16 q.
__global__ __launch_bounds__(256) void attn_kernel(
    const unsigned short* __restrict__ qk, const unsigned short* __restrict__ vt,
    unsigned short* __restrict__ y_t)
{
    __shared__ __align__(16) unsigned short kbuf[2][64 * 32];  // [t][d], chunk^=(t&3)
    __shared__ __align__(16) unsigned short vbuf[2][64 * 64];  // [d][t], chunk^=(d&7)

    const int tid = threadIdx.x, wid = tid >> 6, lane = tid & 63;
    const int g = lane >> 4, cc = lane & 15;
    const int pair = blockIdx.x;
    const int q0 = blockIdx.y * 64 + wid * 16;
    const int n = pair & 3, b = pair >> 2;

    const unsigned short* qkb = qk + (size_t)pair * 1600 * 64;
    const unsigned short* vtb = vt + (size_t)pair * 64 * 1600;

    bf16x8 bq = *(const bf16x8*)(qkb + (size_t)(q0 + cc) * 64 + 8 * g);

    const int kt_row = tid >> 2, kt_chk = tid & 3;
    const unsigned short* ksrc0 = qkb + (size_t)kt_row * 64 + 32 + (kt_chk ^ (kt_row & 3)) * 8;
    const int vd_row = tid >> 3, vd_chk = tid & 7;
    const unsigned short* vsrc0 = vtb + (size_t)vd_row * 1600 + (vd_chk ^ (vd_row & 7)) * 8;

    #define STAGE(bufi, kk0)                                                            \
        do {                                                                            \
            __builtin_amdgcn_global_load_lds(                                           \
                (g_u32*)(ksrc0 + (size_t)(kk0) * 64),                                   \
                (l_u32*)(&kbuf[bufi][wid * 512]), 16, 0, 0);                            \
            __builtin_amdgcn_global_load_lds(                                           \
                (g_u32*)(vsrc0 + (kk0)),                                                \
                (l_u32*)(&vbuf[bufi][wid * 512]), 16, 0, 0);                            \
            __builtin_amdgcn_global_load_lds(                                           \
                (g_u32*)(vsrc0 + (size_t)32 * 1600 + (kk0)),                            \
                (l_u32*)(&vbuf[bufi][2048 + wid * 512]), 16, 0, 0);                     \
        } while (0)

    STAGE(0, 0);
    __syncthreads();

    const f32x4 fz = {0.f, 0.f, 0.f, 0.f};
    const short one_bf = (short)0x3F80;
    const bf16x8 ones = {one_bf, one_bf, one_bf, one_bf, one_bf, one_bf, one_bf, one_bf};
    f32x4 o[4] = {fz, fz, fz, fz};
    f32x4 sumacc = fz;
    int cur = 0;

    for (int kt = 0; kt < 25; ++kt) {
        if (kt + 1 < 25) STAGE(cur ^ 1, (kt + 1) * 64);

        bf16x8 kf[4], vf[8];
        #pragma unroll
        for (int f = 0; f < 4; ++f) {
            int t = 16 * f + cc;
            kf[f] = *(const bf16x8*)&kbuf[cur][t * 32 + (g ^ (t & 3)) * 8];
        }
        #pragma unroll
        for (int f2 = 0; f2 < 4; ++f2) {
            int d = 16 * f2 + cc;
            #pragma unroll
            for (int s2 = 0; s2 < 2; ++s2)
                vf[f2 * 2 + s2] = *(const bf16x8*)&vbuf[cur][d * 64 + (((4 * s2 + g) ^ (d & 7)) * 8)];
        }

        // ---- QK^T ----
        f32x4 s4[4];
        __builtin_amdgcn_s_setprio(1);
        #pragma unroll
        for (int f = 0; f < 4; ++f)
            s4[f] = __builtin_amdgcn_mfma_f32_16x16x32_bf16(kf[f], bq, fz, 0, 0, 0);
        __builtin_amdgcn_s_setprio(0);

        // ---- exp2 + pack + permlane transpose ----
        unsigned c2[4][2];
        #pragma unroll
        for (int f = 0; f < 4; ++f) {
            float p0 = exp2f(s4[f][0]), p1 = exp2f(s4[f][1]);
            float p2 = exp2f(s4[f][2]), p3 = exp2f(s4[f][3]);
            c2[f][0] = pkbf(p0, p1);
            c2[f][1] = pkbf(p2, p3);
        }
        unsigned pb_u[2][4];
        #pragma unroll
        for (int s2 = 0; s2 < 2; ++s2) {
            const int fA = 2 * s2, fB = 2 * s2 + 1;
            u32x2 xy0 = __builtin_amdgcn_permlane32_swap(c2[fA][0], c2[fB][0], false, false);
            u32x2 xy1 = __builtin_amdgcn_permlane32_swap(c2[fA][1], c2[fB][1], false, false);
            u32x2 w02 = __builtin_amdgcn_permlane16_swap(xy0.x, xy0.y, false, false);
            u32x2 w13 = __builtin_amdgcn_permlane16_swap(xy1.x, xy1.y, false, false);
            pb_u[s2][0] = w02.x;
            pb_u[s2][1] = w13.x;
            pb_u[s2][2] = w02.y;
            pb_u[s2][3] = w13.y;
        }

        // ---- PV + row-sum-by-ones ----
        __builtin_amdgcn_s_setprio(1);
        #pragma unroll
        for (int s2 = 0; s2 < 2; ++s2) {
            union { unsigned u[4]; bf16x8 v; } pb;
            #pragma unroll
            for (int j = 0; j < 4; ++j) pb.u[j] = pb_u[s2][j];
            #pragma unroll
            for (int f2 = 0; f2 < 4; ++f2)
                o[f2] = __builtin_amdgcn_mfma_f32_16x16x32_bf16(vf[f2 * 2 + s2], pb.v, o[f2], 0, 0, 0);
            sumacc = __builtin_amdgcn_mfma_f32_16x16x32_bf16(ones, pb.v, sumacc, 0, 0, 0);
        }
        __builtin_amdgcn_s_setprio(0);

        __syncthreads();
        cur ^= 1;
    }
    #undef STAGE

    // ---- epilogue: lane-local normalizer (sumacc col q = cc) ----
    float il = 1.f / sumacc[0];
    unsigned short* yb = y_t + ((size_t)b * 1600 + q0 + cc) * 256 + n * 64;
    #pragma unroll
    for (int f2 = 0; f2 < 4; ++f2) {
        u16x4 st;
        #pragma unroll
        for (int r = 0; r < 4; ++r) st[r] = f2bf(o[f2][r] * il);
        *(u16x4*)(yb + 16 * f2 + 4 * g) = st;
    }
}

// ---------- y += BN(depthwise3x3(v)), in place on y_t, v2 channel-major ----------
__global__ __launch_bounds__(256) void dw_kernel(
    const unsigned short* __restrict__ v2, unsigned short* __restrict__ y_t,
    const float* __restrict__ cw, const float* __restrict__ gg,
    const float* __restrict__ bet, const float* __restrict__ mm,
    const float* __restrict__ vv)
{
    const int tid = threadIdx.x;
    const int gl = blockIdx.x * 64 + (tid & 63);
    const int c0 = blockIdx.y * 32 + (tid >> 6) * 8;
    const int b = gl / 1600;
    const int l = gl - b * 1600;
    const int h = l / 40, w = l - h * 40;

    float s[8];
    #pragma unroll
    for (int i = 0; i < 8; ++i) s[i] = 0.f;
    #pragma unroll
    for (int kh = -1; kh <= 1; ++kh) {
        int hh = h + kh;
        if (hh < 0 || hh >= 40) continue;
        #pragma unroll
        for (int kw = -1; kw <= 1; ++kw) {
            int ww = w + kw;
            if (ww < 0 || ww >= 40) continue;
            u16x8 vv8 = *(const u16x8*)(v2 + (size_t)(gl + kh * 40 + kw) * 256 + c0);
            const int tap = (kh + 1) * 3 + (kw + 1);
            #pragma unroll
            for (int i = 0; i < 8; ++i)
                s[i] = fmaf(bf2f(vv8[i]), cw[(c0 + i) * 9 + tap], s[i]);
        }
    }
    u16x8 yv = *(const u16x8*)(y_t + (size_t)gl * 256 + c0);
    u16x8 out;
    #pragma unroll
    for (int i = 0; i < 8; ++i) {
        int c = c0 + i;
        float iv = gg[c] * rsqrtf(vv[c] + EPS);
        out[i] = f2bf(bf2f(yv[i]) + s[i] * iv + (bet[c] - mm[c] * iv));
    }
    *(u16x8*)(y_t + (size_t)gl * 256 + c0) = out;
}

// ---------- out = BN(cb2_w @ y) via MFMA, 32o x 64l per wave ----------
__global__ __launch_bounds__(256) void out_gemm_kernel(
    const unsigned short* __restrict__ wcb, const unsigned short* __restrict__ y_t,
    const float* __restrict__ gg, const float* __restrict__ bet,
    const float* __restrict__ mm, const float* __restrict__ vv,
    float* __restrict__ out)
{
    const int tid = threadIdx.x, wid = tid >> 6, lane = tid & 63;
    const int g = lane >> 4, cc = lane & 15;
    const int gl0 = blockIdx.x * 128 + (wid & 1) * 64;
    const int o_base = blockIdx.y * 64 + (wid >> 1) * 32;

    const unsigned short* wb0 = wcb + (size_t)(o_base + cc) * 256;
    const unsigned short* wb1 = wcb + (size_t)(o_base + 16 + cc) * 256;
    const unsigned short* yb  = y_t + (size_t)(gl0 + cc) * 256;

    const f32x4 fz = {0.f, 0.f, 0.f, 0.f};
    f32x4 acc[2][4] = {{fz, fz, fz, fz}, {fz, fz, fz, fz}};
    #pragma unroll 4
    for (int kk = 0; kk < 256; kk += 32) {
        bf16x8 a0 = *(const bf16x8*)(wb0 + kk + 8 * g);
        bf16x8 a1 = *(const bf16x8*)(wb1 + kk + 8 * g);
        #pragma unroll
        for (int f = 0; f < 4; ++f) {
            bf16x8 bfr = *(const bf16x8*)(yb + (size_t)f * 16 * 256 + kk + 8 * g);
            acc[0][f] = __builtin_amdgcn_mfma_f32_16x16x32_bf16(a0, bfr, acc[0][f], 0, 0, 0);
            acc[1][f] = __builtin_amdgcn_mfma_f32_16x16x32_bf16(a1, bfr, acc[1][f], 0, 0, 0);
        }
    }
    #pragma unroll
    for (int i = 0; i < 2; ++i) {
        #pragma unroll
        for (int r = 0; r < 4; ++r) {
            int oc = o_base + 16 * i + 4 * g + r;
            float iv = gg[oc] * rsqrtf(vv[oc] + EPS);
            float bs = bet[oc] - mm[oc] * iv;
            #pragma unroll
            for (int f = 0; f < 4; ++f) {
                int gl = gl0 + 16 * f + cc;
                int b  = gl / 1600;
                int ll = gl - b * 1600;
                out[((size_t)b * 256 + oc) * 1600 + ll] = acc[i][f][r] * iv + bs;
            }
        }
    }
}

extern "C" void kernel_launch(void* const* d_in, const int* in_sizes, int n_in,
                              void* d_out, int out_size, void* d_ws, size_t ws_size,
                              hipStream_t stream) {
    const float* x     = (const float*)d_in[0];
    const float* qkv_w = (const float*)d_in[1];
    const float* qkv_g = (const float*)d_in[2];
    const float* qkv_b = (const float*)d_in[3];
    const float* qkv_m = (const float*)d_in[4];
    const float* qkv_v = (const float*)d_in[5];
    const float* cb1_w = (const float*)d_in[6];
    const float* cb1_g = (const float*)d_in[7];
    const float* cb1_b = (const float*)d_in[8];
    const float* cb1_m = (const float*)d_in[9];
    const float* cb1_v = (const float*)d_in[10];
    const float* cb2_w = (const float*)d_in[11];
    const float* cb2_g = (const float*)d_in[12];
    const float* cb2_b = (const float*)d_in[13];
    const float* cb2_m = (const float*)d_in[14];
    const float* cb2_v = (const float*)d_in[15];
    float* out = (float*)d_out;

    unsigned short* ws16 = (unsigned short*)d_ws;
    const size_t N16 = 3276800;                 // 8*1600*256
    unsigned short* xt  = ws16;                 // [gl][256]
    unsigned short* qk  = ws16 + N16;           // [pair][l][64]
    unsigned short* vt  = ws16 + 2 * N16;       // [pair][d][l]
    unsigned short* y_t = ws16 + 3 * N16;       // [gl][256] (dw in-place)
    unsigned short* v2  = ws16 + 4 * N16;       // [gl][256] v channel-major
    unsigned short* wqb = ws16 + 5 * N16;       // 512*256
    unsigned short* wcb = wqb + 131072;         // 256*256

    convw_kernel<<<dim3(192), 256, 0, stream>>>(qkv_w, cb2_w, wqb, wcb);
    convx_kernel<<<dim3(25, 4, 8), 256, 0, stream>>>(x, xt);
    qkv_gemm_kernel<<<dim3(100, 8), 256, 0, stream>>>(wqb, xt, qkv_g, qkv_b, qkv_m, qkv_v, qk, vt, v2);
    attn_kernel<<<dim3(32, 25), 256, 0, stream>>>(qk, vt, y_t);
    dw_kernel<<<dim3(200, 8), 256, 0, stream>>>(v2, y_t, cb1_w, cb1_g, cb1_b, cb1_m, cb1_v);
    out_gemm_kernel<<<dim3(100, 4), 256, 0, stream>>>(wcb, y_t, cb2_g, cb2_b, cb2_m, cb2_v, out);
}